// Round 1
// baseline (272.769 us; speedup 1.0000x reference)
//
#include <hip/hip_runtime.h>
#include <math.h>

#define NN 4096
#define DD 128

// One 128x128 output tile per block; 256 threads, 8x8 per thread.
// C[i,j] = sum_d F1[d,i]*F2[d,j]; loss += -S[i,j]*0.5*C + log(1 + 0.5*C + eps)
__global__ __launch_bounds__(256, 1)
void gemm_loss_kernel(const float* __restrict__ S, const float* __restrict__ F1,
                      const float* __restrict__ F2, float eps, double* __restrict__ accum)
{
    __shared__ float s1[DD][128];
    __shared__ float s2[DD][128];
    __shared__ float red[4];
    const int t  = threadIdx.x;
    const int i0 = blockIdx.y * 128;
    const int j0 = blockIdx.x * 128;

    // Stage F1/F2 tiles (128 rows x 128 cols each). Coalesced float4 rows.
    {
        const int c4 = (t & 31) * 4;
        const int r0 = t >> 5;
        #pragma unroll
        for (int p = 0; p < 16; ++p) {
            const int dd = p * 8 + r0;
            *(float4*)&s1[dd][c4] = *(const float4*)&F1[(long)dd * NN + i0 + c4];
            *(float4*)&s2[dd][c4] = *(const float4*)&F2[(long)dd * NN + j0 + c4];
        }
    }
    __syncthreads();

    const int tx = t & 15;   // j sub-group (fast dim -> coalesced S reads)
    const int ty = t >> 4;   // i sub-group

    // Prefetch this thread's S sub-tile (8 i-rows x 2 float4 j-groups) so the
    // HBM latency hides under the FMA loop below.
    float4 sv[8][2];
    #pragma unroll
    for (int a = 0; a < 8; ++a) {
        const int  i    = i0 + ty * 4 + ((a >> 2) << 6) + (a & 3);
        const long base = (long)i * NN + j0 + tx * 4;
        sv[a][0] = *(const float4*)&S[base];
        sv[a][1] = *(const float4*)&S[base + 64];
    }

    float acc[8][8];
    #pragma unroll
    for (int a = 0; a < 8; ++a)
        #pragma unroll
        for (int b = 0; b < 8; ++b) acc[a][b] = 0.f;

    #pragma unroll 2
    for (int d = 0; d < DD; ++d) {
        const float4 a0 = *(const float4*)&s1[d][ty * 4];
        const float4 a1 = *(const float4*)&s1[d][ty * 4 + 64];
        const float4 b0 = *(const float4*)&s2[d][tx * 4];
        const float4 b1 = *(const float4*)&s2[d][tx * 4 + 64];
        const float av[8] = {a0.x, a0.y, a0.z, a0.w, a1.x, a1.y, a1.z, a1.w};
        const float bv[8] = {b0.x, b0.y, b0.z, b0.w, b1.x, b1.y, b1.z, b1.w};
        #pragma unroll
        for (int a = 0; a < 8; ++a)
            #pragma unroll
            for (int b = 0; b < 8; ++b)
                acc[a][b] = fmaf(av[a], bv[b], acc[a][b]);
    }

    float lsum = 0.f;
    #pragma unroll
    for (int a = 0; a < 8; ++a) {
        #pragma unroll
        for (int jg = 0; jg < 2; ++jg) {
            const float4 s = sv[a][jg];
            const float o0 = 0.5f * acc[a][jg * 4 + 0];
            const float o1 = 0.5f * acc[a][jg * 4 + 1];
            const float o2 = 0.5f * acc[a][jg * 4 + 2];
            const float o3 = 0.5f * acc[a][jg * 4 + 3];
            lsum += fmaf(-s.x, o0, __logf(1.0f + o0 + eps));
            lsum += fmaf(-s.y, o1, __logf(1.0f + o1 + eps));
            lsum += fmaf(-s.z, o2, __logf(1.0f + o2 + eps));
            lsum += fmaf(-s.w, o3, __logf(1.0f + o3 + eps));
        }
    }

    float v = lsum;
    #pragma unroll
    for (int off = 32; off; off >>= 1) v += __shfl_down(v, off);
    if ((t & 63) == 0) red[t >> 6] = v;
    __syncthreads();
    if (t == 0) {
        const float tot = red[0] + red[1] + red[2] + red[3];
        atomicAdd(accum, (double)tot);
    }
}

// ||FP-B||^2 and ||FM-B||^2 partial sums (sqrt applied in finalize).
__global__ __launch_bounds__(256)
void bqc_kernel(const float* __restrict__ FP, const float* __restrict__ FM,
                const float* __restrict__ B, double* __restrict__ ws)
{
    __shared__ float red1[4], red2[4];
    const int n4 = DD * NN / 4;
    float s1 = 0.f, s2 = 0.f;
    for (int i = blockIdx.x * blockDim.x + threadIdx.x; i < n4;
         i += gridDim.x * blockDim.x) {
        const float4 p = ((const float4*)FP)[i];
        const float4 m = ((const float4*)FM)[i];
        const float4 b = ((const float4*)B)[i];
        float d;
        d = p.x - b.x; s1 += d * d;  d = p.y - b.y; s1 += d * d;
        d = p.z - b.z; s1 += d * d;  d = p.w - b.w; s1 += d * d;
        d = m.x - b.x; s2 += d * d;  d = m.y - b.y; s2 += d * d;
        d = m.z - b.z; s2 += d * d;  d = m.w - b.w; s2 += d * d;
    }
    const int t = threadIdx.x;
    #pragma unroll
    for (int off = 32; off; off >>= 1) {
        s1 += __shfl_down(s1, off);
        s2 += __shfl_down(s2, off);
    }
    if ((t & 63) == 0) { red1[t >> 6] = s1; red2[t >> 6] = s2; }
    __syncthreads();
    if (t == 0) {
        atomicAdd(&ws[1], (double)(red1[0] + red1[1] + red1[2] + red1[3]));
        atomicAdd(&ws[2], (double)(red2[0] + red2[1] + red2[2] + red2[3]));
    }
}

// sum over rows of (row-sum)^2 for FP (blocks 0..127) and FM (blocks 128..255)
__global__ __launch_bounds__(256)
void fdc_kernel(const float* __restrict__ FP, const float* __restrict__ FM,
                double* __restrict__ ws)
{
    __shared__ float red[4];
    const float* F = (blockIdx.x >= DD) ? FM : FP;
    const int row = blockIdx.x & (DD - 1);
    float s = 0.f;
    const float4* rowp = (const float4*)&F[(long)row * NN];
    for (int i = threadIdx.x; i < NN / 4; i += blockDim.x) {
        const float4 v = rowp[i];
        s += v.x + v.y + v.z + v.w;
    }
    const int t = threadIdx.x;
    #pragma unroll
    for (int off = 32; off; off >>= 1) s += __shfl_down(s, off);
    if ((t & 63) == 0) red[t >> 6] = s;
    __syncthreads();
    if (t == 0) {
        const double rs = (double)(red[0] + red[1] + red[2] + red[3]);
        atomicAdd(&ws[3], rs * rs);
    }
}

__global__ void finalize_kernel(const double* __restrict__ ws, float* __restrict__ out)
{
    if (threadIdx.x == 0 && blockIdx.x == 0)
        out[0] = (float)(ws[0] + ws[3] + sqrt(ws[1]) + sqrt(ws[2]));
}

extern "C" void kernel_launch(void* const* d_in, const int* in_sizes, int n_in,
                              void* d_out, int out_size, void* d_ws, size_t ws_size,
                              hipStream_t stream)
{
    const float* SU = (const float*)d_in[0];
    const float* SP = (const float*)d_in[1];
    const float* SM = (const float*)d_in[2];
    const float* FP = (const float*)d_in[3];
    const float* FM = (const float*)d_in[4];
    const float* B  = (const float*)d_in[5];
    float*  out = (float*)d_out;
    double* ws  = (double*)d_ws;

    hipMemsetAsync(d_ws, 0, 4 * sizeof(double), stream);

    dim3 grid(NN / 128, NN / 128);
    gemm_loss_kernel<<<grid, 256, 0, stream>>>(SU, FP, FM, 0.0f, ws);       // IRSC
    gemm_loss_kernel<<<grid, 256, 0, stream>>>(SP, FP, FP, 1e-8f, ws);      // IASC-P
    gemm_loss_kernel<<<grid, 256, 0, stream>>>(SM, FM, FM, 1e-8f, ws);      // IASC-M
    bqc_kernel<<<512, 256, 0, stream>>>(FP, FM, B, ws);
    fdc_kernel<<<256, 256, 0, stream>>>(FP, FM, ws);
    finalize_kernel<<<1, 64, 0, stream>>>(ws, out);
}

// Round 2
// 100.933 us; speedup vs baseline: 2.7025x; 2.7025x over previous
//
#include <hip/hip_runtime.h>
#include <hip/hip_bf16.h>
#include <math.h>

#define NN 4096
#define DD 128

typedef __attribute__((ext_vector_type(8))) short bf16x8;
typedef __attribute__((ext_vector_type(4))) float f32x4;

// One 128x128 output tile per block; 256 threads = 4 waves, each wave a 64x64
// sub-tile as 4x4 fragments of mfma_f32_16x16x32_bf16.
// C[i,j] = sum_d F1[d,i]*F2[d,j]; loss += -S[i,j]*0.5*C + log(1 + 0.5*C + eps)
__global__ __launch_bounds__(256, 2)
void gemm_loss_mfma(const float* __restrict__ S, const float* __restrict__ F1,
                    const float* __restrict__ F2, float eps, double* __restrict__ accum)
{
    // Transposed bf16 tiles: row = i (or j), 128 bf16 of d per row (256 B).
    // 16B chunk q (=d/8) stored at byte  row*256 + ((q ^ (row&15))<<4)  so both
    // staging writes and fragment reads spread across banks (~2-way, free).
    __shared__ char lds[2][128 * 256];
    __shared__ float red[4];
    const int t  = threadIdx.x;
    const int i0 = blockIdx.y * 128;
    const int j0 = blockIdx.x * 128;

    // ---- stage both tiles: global f32 (column reads, coalesced across threads)
    // ---- -> bf16 -> swizzled transposed LDS
    {
        const int il   = t & 127;      // row (i or j local)
        const int half = t >> 7;       // which 64-d half this thread stages
        const float* c1 = F1 + i0 + il;
        const float* c2 = F2 + j0 + il;
        char* r1 = lds[0] + il * 256;
        char* r2 = lds[1] + il * 256;
        #pragma unroll
        for (int it = 0; it < 8; ++it) {
            const int q  = half * 8 + it;
            const int d0 = q * 8;
            float a[8], b[8];
            #pragma unroll
            for (int j = 0; j < 8; ++j) {
                a[j] = c1[(long)(d0 + j) * NN];
                b[j] = c2[(long)(d0 + j) * NN];
            }
            union { __hip_bfloat162 h[4]; bf16x8 v; } pa, pb;
            #pragma unroll
            for (int j = 0; j < 4; ++j) {
                pa.h[j] = __float22bfloat162_rn(make_float2(a[2*j], a[2*j+1]));
                pb.h[j] = __float22bfloat162_rn(make_float2(b[2*j], b[2*j+1]));
            }
            const int off = (q ^ (il & 15)) << 4;
            *(bf16x8*)(r1 + off) = pa.v;
            *(bf16x8*)(r2 + off) = pb.v;
        }
    }
    __syncthreads();

    const int lane = t & 63;
    const int wid  = t >> 6;
    const int wr   = wid >> 1, wc = wid & 1;   // 2x2 waves of 64x64
    const int l15  = lane & 15, l4 = lane >> 4;

    // ---- prefetch this lane's S sub-tile (C/D layout: col=lane&15,
    // ---- row=(lane>>4)*4+reg) so HBM/L3 latency hides under the MFMAs.
    float sreg[4][4][4];   // [m16][n16][reg]
    #pragma unroll
    for (int am = 0; am < 4; ++am)
        #pragma unroll
        for (int r = 0; r < 4; ++r) {
            const long gi   = (long)(i0 + wr * 64 + am * 16 + l4 * 4 + r);
            const long base = gi * NN + j0 + wc * 64 + l15;
            #pragma unroll
            for (int bn = 0; bn < 4; ++bn)
                sreg[am][bn][r] = S[base + bn * 16];
        }

    // ---- MFMA: acc[m][n] over 4 k-blocks of 32
    f32x4 acc[4][4] = {};
    #pragma unroll
    for (int kb = 0; kb < 4; ++kb) {
        bf16x8 af[4], bg[4];
        #pragma unroll
        for (int m = 0; m < 4; ++m) {
            const int ia = wr * 64 + m * 16 + l15;
            af[m] = *(const bf16x8*)(lds[0] + ia * 256 + (((kb * 4 + l4) ^ l15) << 4));
            const int jb = wc * 64 + m * 16 + l15;
            bg[m] = *(const bf16x8*)(lds[1] + jb * 256 + (((kb * 4 + l4) ^ l15) << 4));
        }
        #pragma unroll
        for (int m = 0; m < 4; ++m)
            #pragma unroll
            for (int n = 0; n < 4; ++n)
                acc[m][n] = __builtin_amdgcn_mfma_f32_16x16x32_bf16(af[m], bg[n], acc[m][n], 0, 0, 0);
    }

    // ---- epilogue: loss terms + reduction
    float lsum = 0.f;
    #pragma unroll
    for (int m = 0; m < 4; ++m)
        #pragma unroll
        for (int n = 0; n < 4; ++n)
            #pragma unroll
            for (int r = 0; r < 4; ++r) {
                const float o = 0.5f * acc[m][n][r];
                lsum += fmaf(-sreg[m][n][r], o, __logf(1.0f + o + eps));
            }

    float v = lsum;
    #pragma unroll
    for (int off = 32; off; off >>= 1) v += __shfl_down(v, off);
    if ((t & 63) == 0) red[t >> 6] = v;
    __syncthreads();
    if (t == 0) {
        const float tot = red[0] + red[1] + red[2] + red[3];
        atomicAdd(accum, (double)tot);
    }
}

// ||FP-B||^2 and ||FM-B||^2 partial sums (sqrt applied in finalize).
__global__ __launch_bounds__(256)
void bqc_kernel(const float* __restrict__ FP, const float* __restrict__ FM,
                const float* __restrict__ B, double* __restrict__ ws)
{
    __shared__ float red1[4], red2[4];
    const int n4 = DD * NN / 4;
    float s1 = 0.f, s2 = 0.f;
    for (int i = blockIdx.x * blockDim.x + threadIdx.x; i < n4;
         i += gridDim.x * blockDim.x) {
        const float4 p = ((const float4*)FP)[i];
        const float4 m = ((const float4*)FM)[i];
        const float4 b = ((const float4*)B)[i];
        float d;
        d = p.x - b.x; s1 += d * d;  d = p.y - b.y; s1 += d * d;
        d = p.z - b.z; s1 += d * d;  d = p.w - b.w; s1 += d * d;
        d = m.x - b.x; s2 += d * d;  d = m.y - b.y; s2 += d * d;
        d = m.z - b.z; s2 += d * d;  d = m.w - b.w; s2 += d * d;
    }
    const int t = threadIdx.x;
    #pragma unroll
    for (int off = 32; off; off >>= 1) {
        s1 += __shfl_down(s1, off);
        s2 += __shfl_down(s2, off);
    }
    if ((t & 63) == 0) { red1[t >> 6] = s1; red2[t >> 6] = s2; }
    __syncthreads();
    if (t == 0) {
        atomicAdd(&ws[1], (double)(red1[0] + red1[1] + red1[2] + red1[3]));
        atomicAdd(&ws[2], (double)(red2[0] + red2[1] + red2[2] + red2[3]));
    }
}

// sum over rows of (row-sum)^2 for FP (blocks 0..127) and FM (blocks 128..255)
__global__ __launch_bounds__(256)
void fdc_kernel(const float* __restrict__ FP, const float* __restrict__ FM,
                double* __restrict__ ws)
{
    __shared__ float red[4];
    const float* F = (blockIdx.x >= DD) ? FM : FP;
    const int row = blockIdx.x & (DD - 1);
    float s = 0.f;
    const float4* rowp = (const float4*)&F[(long)row * NN];
    for (int i = threadIdx.x; i < NN / 4; i += blockDim.x) {
        const float4 v = rowp[i];
        s += v.x + v.y + v.z + v.w;
    }
    const int t = threadIdx.x;
    #pragma unroll
    for (int off = 32; off; off >>= 1) s += __shfl_down(s, off);
    if ((t & 63) == 0) red[t >> 6] = s;
    __syncthreads();
    if (t == 0) {
        const double rs = (double)(red[0] + red[1] + red[2] + red[3]);
        atomicAdd(&ws[3], rs * rs);
    }
}

__global__ void finalize_kernel(const double* __restrict__ ws, float* __restrict__ out)
{
    if (threadIdx.x == 0 && blockIdx.x == 0)
        out[0] = (float)(ws[0] + ws[3] + sqrt(ws[1]) + sqrt(ws[2]));
}

extern "C" void kernel_launch(void* const* d_in, const int* in_sizes, int n_in,
                              void* d_out, int out_size, void* d_ws, size_t ws_size,
                              hipStream_t stream)
{
    const float* SU = (const float*)d_in[0];
    const float* SP = (const float*)d_in[1];
    const float* SM = (const float*)d_in[2];
    const float* FP = (const float*)d_in[3];
    const float* FM = (const float*)d_in[4];
    const float* B  = (const float*)d_in[5];
    float*  out = (float*)d_out;
    double* ws  = (double*)d_ws;

    hipMemsetAsync(d_ws, 0, 4 * sizeof(double), stream);

    dim3 grid(NN / 128, NN / 128);
    gemm_loss_mfma<<<grid, 256, 0, stream>>>(SU, FP, FM, 0.0f, ws);       // IRSC
    gemm_loss_mfma<<<grid, 256, 0, stream>>>(SP, FP, FP, 1e-8f, ws);      // IASC-P
    gemm_loss_mfma<<<grid, 256, 0, stream>>>(SM, FM, FM, 1e-8f, ws);      // IASC-M
    bqc_kernel<<<512, 256, 0, stream>>>(FP, FM, B, ws);
    fdc_kernel<<<256, 256, 0, stream>>>(FP, FM, ws);
    finalize_kernel<<<1, 64, 0, stream>>>(ws, out);
}

// Round 3
// 98.690 us; speedup vs baseline: 2.7639x; 1.0227x over previous
//
#include <hip/hip_runtime.h>
#include <hip/hip_bf16.h>
#include <math.h>

#define NN 4096
#define DD 128

typedef __attribute__((ext_vector_type(8))) short bf16x8;
typedef __attribute__((ext_vector_type(4))) float f32x4;

__device__ __forceinline__ void gload_lds16(const float* g, float* l) {
    __builtin_amdgcn_global_load_lds((const __attribute__((address_space(1))) char*)g,
                                     (__attribute__((address_space(3))) char*)l, 16, 0, 0);
}

// ---------------- fast path ----------------
// Pre-convert F (f32 [d][i], column-read coalesced) -> bf16 transposed [i][d].
__global__ __launch_bounds__(256)
void convert_kernel(const float* __restrict__ FP, const float* __restrict__ FM,
                    __hip_bfloat16* __restrict__ FPb, __hip_bfloat16* __restrict__ FMb)
{
    const float* src = blockIdx.y ? FM : FP;
    __hip_bfloat16* dst = blockIdx.y ? FMb : FPb;
    const int t  = threadIdx.x;
    const int il = t & 127;
    const int dh = t >> 7;
    const int i  = blockIdx.x * 128 + il;
    #pragma unroll
    for (int it = 0; it < 8; ++it) {
        const int d0 = dh * 64 + it * 8;
        union { __hip_bfloat162 h[4]; bf16x8 v; } p;
        #pragma unroll
        for (int j = 0; j < 4; ++j) {
            const float a = src[(long)(d0 + 2*j)     * NN + i];
            const float b = src[(long)(d0 + 2*j + 1) * NN + i];
            p.h[j] = __float22bfloat162_rn(make_float2(a, b));
        }
        *(bf16x8*)&dst[(long)i * DD + d0] = p.v;
    }
}

// One 128x128 tile per block; 4 waves = 2x2 of 64x64. Fragments straight from
// L2-resident bf16 F; S streamed to LDS with global_load_lds and consumed in
// the epilogue. All three gemms merged via blockIdx.z.
__global__ __launch_bounds__(256, 2)
void gemm_loss_mfma2(const float* __restrict__ SU, const float* __restrict__ SP,
                     const float* __restrict__ SM,
                     const __hip_bfloat16* __restrict__ FPb,
                     const __hip_bfloat16* __restrict__ FMb,
                     double* __restrict__ accum)
{
    __shared__ float sS[4][64 * 64];   // per-wave 64x64 f32 S quadrant
    __shared__ float red[4];
    const int t    = threadIdx.x;
    const int lane = t & 63, wid = t >> 6;
    const int wr   = wid >> 1, wc = wid & 1;
    const int l15  = lane & 15, l4 = lane >> 4;
    const int z    = blockIdx.z;
    const float* S  = (z == 0) ? SU : (z == 1) ? SP : SM;
    const short* Fa = (const short*)((z == 2) ? FMb : FPb);
    const short* Fb = (const short*)((z == 0) ? FMb : (z == 1) ? FPb : (const __hip_bfloat16*)FMb);
    const float eps = (z == 0) ? 0.0f : 1e-8f;
    const int i0 = blockIdx.y * 128;
    const int j0 = blockIdx.x * 128;

    // ---- 1) issue ALL fragment loads first (vmcnt is FIFO: these must precede
    // ---- the S stream so MFMAs wait only on them)
    bf16x8 af[4][4], bg[4][4];   // [kb][m]
    {
        const long ibase = (long)(i0 + wr * 64 + l15) * DD;
        const long jbase = (long)(j0 + wc * 64 + l15) * DD;
        #pragma unroll
        for (int kb = 0; kb < 4; ++kb) {
            const int ko = kb * 32 + l4 * 8;
            #pragma unroll
            for (int m = 0; m < 4; ++m) {
                af[kb][m] = *(const bf16x8*)&Fa[ibase + (long)m * 16 * DD + ko];
                bg[kb][m] = *(const bf16x8*)&Fb[jbase + (long)m * 16 * DD + ko];
            }
        }
    }

    // ---- 2) stream this wave's own 64x64 S quadrant into LDS (16 x 1KB).
    // LDS dest is wave-uniform base + lane*16; global src is per-lane.
    {
        float* qb = sS[wid];
        const float* gb = S + (long)(i0 + wr * 64 + l4) * NN + j0 + wc * 64 + l15 * 4;
        #pragma unroll
        for (int q = 0; q < 16; ++q)
            gload_lds16(gb + (long)q * 4 * NN, qb + q * 256);
    }
    __builtin_amdgcn_sched_barrier(0);

    // ---- 3) MFMAs (compiler waits counted vmcnt for frags; S stays in flight)
    f32x4 acc[4][4] = {};
    #pragma unroll
    for (int kb = 0; kb < 4; ++kb)
        #pragma unroll
        for (int m = 0; m < 4; ++m)
            #pragma unroll
            for (int n = 0; n < 4; ++n)
                acc[m][n] = __builtin_amdgcn_mfma_f32_16x16x32_bf16(af[kb][m], bg[kb][n], acc[m][n], 0, 0, 0);

    // ---- 4) epilogue: wave reads only its own quadrant -> no barrier needed
    asm volatile("s_waitcnt vmcnt(0)" ::: "memory");
    __builtin_amdgcn_sched_barrier(0);

    float lsum = 0.f;
    const float* q = sS[wid];
    #pragma unroll
    for (int m = 0; m < 4; ++m)
        #pragma unroll
        for (int n = 0; n < 4; ++n) {
            const int base = (m * 16 + l4 * 4) * 64 + n * 16 + l15;
            #pragma unroll
            for (int r = 0; r < 4; ++r) {
                const float s = q[base + r * 64];
                const float o = 0.5f * acc[m][n][r];
                lsum += fmaf(-s, o, __logf(1.0f + o + eps));
            }
        }

    float v = lsum;
    #pragma unroll
    for (int off = 32; off; off >>= 1) v += __shfl_down(v, off);
    if ((t & 63) == 0) red[t >> 6] = v;
    __syncthreads();
    if (t == 0) {
        const float tot = red[0] + red[1] + red[2] + red[3];
        atomicAdd(accum, (double)tot);
    }
}

// ---------------- fallback path (round-2 kernel, used if ws too small) ------
__global__ __launch_bounds__(256, 2)
void gemm_loss_mfma(const float* __restrict__ S, const float* __restrict__ F1,
                    const float* __restrict__ F2, float eps, double* __restrict__ accum)
{
    __shared__ char lds[2][128 * 256];
    __shared__ float red[4];
    const int t  = threadIdx.x;
    const int i0 = blockIdx.y * 128;
    const int j0 = blockIdx.x * 128;
    {
        const int il   = t & 127;
        const int half = t >> 7;
        const float* c1 = F1 + i0 + il;
        const float* c2 = F2 + j0 + il;
        char* r1 = lds[0] + il * 256;
        char* r2 = lds[1] + il * 256;
        #pragma unroll
        for (int it = 0; it < 8; ++it) {
            const int q  = half * 8 + it;
            const int d0 = q * 8;
            float a[8], b[8];
            #pragma unroll
            for (int j = 0; j < 8; ++j) {
                a[j] = c1[(long)(d0 + j) * NN];
                b[j] = c2[(long)(d0 + j) * NN];
            }
            union { __hip_bfloat162 h[4]; bf16x8 v; } pa, pb;
            #pragma unroll
            for (int j = 0; j < 4; ++j) {
                pa.h[j] = __float22bfloat162_rn(make_float2(a[2*j], a[2*j+1]));
                pb.h[j] = __float22bfloat162_rn(make_float2(b[2*j], b[2*j+1]));
            }
            const int off = (q ^ (il & 15)) << 4;
            *(bf16x8*)(r1 + off) = pa.v;
            *(bf16x8*)(r2 + off) = pb.v;
        }
    }
    __syncthreads();
    const int lane = t & 63;
    const int wid  = t >> 6;
    const int wr   = wid >> 1, wc = wid & 1;
    const int l15  = lane & 15, l4 = lane >> 4;
    float sreg[4][4][4];
    #pragma unroll
    for (int am = 0; am < 4; ++am)
        #pragma unroll
        for (int r = 0; r < 4; ++r) {
            const long gi   = (long)(i0 + wr * 64 + am * 16 + l4 * 4 + r);
            const long base = gi * NN + j0 + wc * 64 + l15;
            #pragma unroll
            for (int bn = 0; bn < 4; ++bn)
                sreg[am][bn][r] = S[base + bn * 16];
        }
    f32x4 acc[4][4] = {};
    #pragma unroll
    for (int kb = 0; kb < 4; ++kb) {
        bf16x8 af[4], bgr[4];
        #pragma unroll
        for (int m = 0; m < 4; ++m) {
            const int ia = wr * 64 + m * 16 + l15;
            af[m] = *(const bf16x8*)(lds[0] + ia * 256 + (((kb * 4 + l4) ^ l15) << 4));
            const int jb = wc * 64 + m * 16 + l15;
            bgr[m] = *(const bf16x8*)(lds[1] + jb * 256 + (((kb * 4 + l4) ^ l15) << 4));
        }
        #pragma unroll
        for (int m = 0; m < 4; ++m)
            #pragma unroll
            for (int n = 0; n < 4; ++n)
                acc[m][n] = __builtin_amdgcn_mfma_f32_16x16x32_bf16(af[m], bgr[n], acc[m][n], 0, 0, 0);
    }
    float lsum = 0.f;
    #pragma unroll
    for (int m = 0; m < 4; ++m)
        #pragma unroll
        for (int n = 0; n < 4; ++n)
            #pragma unroll
            for (int r = 0; r < 4; ++r) {
                const float o = 0.5f * acc[m][n][r];
                lsum += fmaf(-sreg[m][n][r], o, __logf(1.0f + o + eps));
            }
    float v = lsum;
    #pragma unroll
    for (int off = 32; off; off >>= 1) v += __shfl_down(v, off);
    if ((t & 63) == 0) red[t >> 6] = v;
    __syncthreads();
    if (t == 0) {
        const float tot = red[0] + red[1] + red[2] + red[3];
        atomicAdd(accum, (double)tot);
    }
}

// ---------------- small kernels ----------------
__global__ __launch_bounds__(256)
void bqc_kernel(const float* __restrict__ FP, const float* __restrict__ FM,
                const float* __restrict__ B, double* __restrict__ ws)
{
    __shared__ float red1[4], red2[4];
    const int n4 = DD * NN / 4;
    float s1 = 0.f, s2 = 0.f;
    for (int i = blockIdx.x * blockDim.x + threadIdx.x; i < n4;
         i += gridDim.x * blockDim.x) {
        const float4 p = ((const float4*)FP)[i];
        const float4 m = ((const float4*)FM)[i];
        const float4 b = ((const float4*)B)[i];
        float d;
        d = p.x - b.x; s1 += d * d;  d = p.y - b.y; s1 += d * d;
        d = p.z - b.z; s1 += d * d;  d = p.w - b.w; s1 += d * d;
        d = m.x - b.x; s2 += d * d;  d = m.y - b.y; s2 += d * d;
        d = m.z - b.z; s2 += d * d;  d = m.w - b.w; s2 += d * d;
    }
    const int t = threadIdx.x;
    #pragma unroll
    for (int off = 32; off; off >>= 1) {
        s1 += __shfl_down(s1, off);
        s2 += __shfl_down(s2, off);
    }
    if ((t & 63) == 0) { red1[t >> 6] = s1; red2[t >> 6] = s2; }
    __syncthreads();
    if (t == 0) {
        atomicAdd(&ws[1], (double)(red1[0] + red1[1] + red1[2] + red1[3]));
        atomicAdd(&ws[2], (double)(red2[0] + red2[1] + red2[2] + red2[3]));
    }
}

__global__ __launch_bounds__(256)
void fdc_kernel(const float* __restrict__ FP, const float* __restrict__ FM,
                double* __restrict__ ws)
{
    __shared__ float red[4];
    const float* F = (blockIdx.x >= DD) ? FM : FP;
    const int row = blockIdx.x & (DD - 1);
    float s = 0.f;
    const float4* rowp = (const float4*)&F[(long)row * NN];
    for (int i = threadIdx.x; i < NN / 4; i += blockDim.x) {
        const float4 v = rowp[i];
        s += v.x + v.y + v.z + v.w;
    }
    const int t = threadIdx.x;
    #pragma unroll
    for (int off = 32; off; off >>= 1) s += __shfl_down(s, off);
    if ((t & 63) == 0) red[t >> 6] = s;
    __syncthreads();
    if (t == 0) {
        const double rs = (double)(red[0] + red[1] + red[2] + red[3]);
        atomicAdd(&ws[3], rs * rs);
    }
}

__global__ void finalize_kernel(const double* __restrict__ ws, float* __restrict__ out)
{
    if (threadIdx.x == 0 && blockIdx.x == 0)
        out[0] = (float)(ws[0] + ws[3] + sqrt(ws[1]) + sqrt(ws[2]));
}

extern "C" void kernel_launch(void* const* d_in, const int* in_sizes, int n_in,
                              void* d_out, int out_size, void* d_ws, size_t ws_size,
                              hipStream_t stream)
{
    const float* SU = (const float*)d_in[0];
    const float* SP = (const float*)d_in[1];
    const float* SM = (const float*)d_in[2];
    const float* FP = (const float*)d_in[3];
    const float* FM = (const float*)d_in[4];
    const float* B  = (const float*)d_in[5];
    float*  out = (float*)d_out;
    double* ws  = (double*)d_ws;

    hipMemsetAsync(d_ws, 0, 4 * sizeof(double), stream);

    const size_t fb_bytes = (size_t)NN * DD * sizeof(__hip_bfloat16);   // 1 MB
    const size_t need     = 4096 + 2 * fb_bytes;

    if (ws_size >= need) {
        __hip_bfloat16* FPb = (__hip_bfloat16*)((char*)d_ws + 4096);
        __hip_bfloat16* FMb = (__hip_bfloat16*)((char*)d_ws + 4096 + fb_bytes);
        convert_kernel<<<dim3(NN / 128, 2), 256, 0, stream>>>(FP, FM, FPb, FMb);
        gemm_loss_mfma2<<<dim3(NN / 128, NN / 128, 3), 256, 0, stream>>>(
            SU, SP, SM, FPb, FMb, ws);
    } else {
        dim3 grid(NN / 128, NN / 128);
        gemm_loss_mfma<<<grid, 256, 0, stream>>>(SU, FP, FM, 0.0f, ws);
        gemm_loss_mfma<<<grid, 256, 0, stream>>>(SP, FP, FP, 1e-8f, ws);
        gemm_loss_mfma<<<grid, 256, 0, stream>>>(SM, FM, FM, 1e-8f, ws);
    }
    bqc_kernel<<<512, 256, 0, stream>>>(FP, FM, B, ws);
    fdc_kernel<<<256, 256, 0, stream>>>(FP, FM, ws);
    finalize_kernel<<<1, 64, 0, stream>>>(ws, out);
}